// Round 5
// baseline (110.316 us; speedup 1.0000x reference)
//
#include <hip/hip_runtime.h>
#include <hip/hip_bf16.h>
#include <stdint.h>

typedef float  f32x4  __attribute__((ext_vector_type(4)));
typedef float  f32x16 __attribute__((ext_vector_type(16)));
typedef _Float16 half8 __attribute__((ext_vector_type(8)));
typedef unsigned int uint32;

#define N1 256
#define N2T 32768
#define BQ 512
#define KT 32
#define TILE_B 16384

// flash LDS: rowA [2][16384] @0 (32 pat rows x 512B, granule g at g^(r&7))
//            memT [2][16384] @32768 (256 d rows x 64B, granule g at g^((d>>1)&3))
#define RA_OFF 0
#define MT_OFF 32768
#define LDS_BYTES 65536

union H4 { _Float16 h[4]; unsigned short s[4]; uint2 u2; };

#define GLD_LDS(gp, lp) __builtin_amdgcn_global_load_lds( \
    (const __attribute__((address_space(1))) void*)(gp), \
    (__attribute__((address_space(3))) void*)(lp), 16, 0, 0)

// ---- prep: Mem f32 -> MemA / MemT (f16, pre-swizzled) + m2 (exact f32). Unchanged. ----
__global__ __launch_bounds__(256) void mhn_prep_k(
    const float* __restrict__ Mem, _Float16* __restrict__ MemA,
    _Float16* __restrict__ MemT, float* __restrict__ m2g)
{
  const int t   = blockIdx.x;
  const int tid = threadIdx.x;
  const int a    = tid >> 4;
  const int dblk = tid & 15;
  const int r0i  = 32*t + 2*a;

  const float* p0 = Mem + (size_t)r0i*N1 + dblk*16;
  const float* p1 = p0 + N1;
  float4 x0[4], x1[4];
  #pragma unroll
  for (int i=0;i<4;i++){ x0[i] = *(const float4*)(p0+4*i); x1[i] = *(const float4*)(p1+4*i); }

  float s0=0.f, s1=0.f;
  H4 h0[4], h1[4];
  #pragma unroll
  for (int i=0;i<4;i++){
    s0 += x0[i].x*x0[i].x + x0[i].y*x0[i].y + x0[i].z*x0[i].z + x0[i].w*x0[i].w;
    s1 += x1[i].x*x1[i].x + x1[i].y*x1[i].y + x1[i].z*x1[i].z + x1[i].w*x1[i].w;
    h0[i].h[0]=(_Float16)x0[i].x; h0[i].h[1]=(_Float16)x0[i].y; h0[i].h[2]=(_Float16)x0[i].z; h0[i].h[3]=(_Float16)x0[i].w;
    h1[i].h[0]=(_Float16)x1[i].x; h1[i].h[1]=(_Float16)x1[i].y; h1[i].h[2]=(_Float16)x1[i].z; h1[i].h[3]=(_Float16)x1[i].w;
  }

  char* bA = (char*)MemA + (size_t)t*TILE_B;
  {
    const int e0 = (2*a)&7, e1 = (2*a+1)&7;
    uint4 wv;
    wv.x=h0[0].u2.x; wv.y=h0[0].u2.y; wv.z=h0[1].u2.x; wv.w=h0[1].u2.y;
    *(uint4*)(bA + (2*a)*512   + (((2*dblk  )^e0)<<4)) = wv;
    wv.x=h0[2].u2.x; wv.y=h0[2].u2.y; wv.z=h0[3].u2.x; wv.w=h0[3].u2.y;
    *(uint4*)(bA + (2*a)*512   + (((2*dblk+1)^e0)<<4)) = wv;
    wv.x=h1[0].u2.x; wv.y=h1[0].u2.y; wv.z=h1[1].u2.x; wv.w=h1[1].u2.y;
    *(uint4*)(bA + (2*a+1)*512 + (((2*dblk  )^e1)<<4)) = wv;
    wv.x=h1[2].u2.x; wv.y=h1[2].u2.y; wv.z=h1[3].u2.x; wv.w=h1[3].u2.y;
    *(uint4*)(bA + (2*a+1)*512 + (((2*dblk+1)^e1)<<4)) = wv;
  }

  char* bT = (char*)MemT + (size_t)t*TILE_B;
  #pragma unroll
  for (int i=0;i<4;i++){
    #pragma unroll
    for (int j=0;j<4;j++){
      const int d = dblk*16 + 4*i + j;
      const uint32 pk = (uint32)h0[i].s[j] | ((uint32)h1[i].s[j] << 16);
      *(uint32*)(bT + d*64 + ((((a>>2) ^ ((d>>1)&3)))<<4) + ((a&3)<<2)) = pk;
    }
  }

  s0 += __shfl_xor(s0,1); s0 += __shfl_xor(s0,2); s0 += __shfl_xor(s0,4); s0 += __shfl_xor(s0,8);
  s1 += __shfl_xor(s1,1); s1 += __shfl_xor(s1,2); s1 += __shfl_xor(s1,4); s1 += __shfl_xor(s1,8);
  if (dblk == 0){ m2g[r0i] = -0.5f*s0; m2g[r0i+1] = -0.5f*s1; }
}

// ---- flash: 32x32x16 MFMA; wave owns 32 q; O computed transposed (rows=d, cols=q) ----
__global__ __launch_bounds__(256, 2) void mhn_flash_k(
    const _Float16* __restrict__ MemA, const _Float16* __restrict__ MemT,
    const float* __restrict__ m2g, const float* __restrict__ v,
    __hip_bfloat16* __restrict__ Opart, float* __restrict__ mpart,
    float* __restrict__ lpart, int CK, int nt)
{
  __shared__ __align__(16) char lds[LDS_BYTES];

  const int tid = threadIdx.x;
  const int w   = tid >> 6;
  const int l   = tid & 63;
  const int row = l & 31;     // A-row lane index (pattern for QK^T, d for PV)
  const int hi  = l >> 5;

  const int nwg = gridDim.x;
  const int bid = blockIdx.x;
  const int s_  = (bid & 7) * (nwg >> 3) + (bid >> 3);
  const int c   = s_ >> 2;
  const int qb  = s_ & 3;

  auto dma = [&](int tt, int bw){
    const size_t off = (size_t)(c*(CK>>5) + tt)*TILE_B + w*4096 + l*16;
    const char* gA = (const char*)MemA + off;
    const char* gT = (const char*)MemT + off;
    char* dA = lds + RA_OFF + bw*TILE_B + w*4096 + l*16;
    char* dT = lds + MT_OFF + bw*TILE_B + w*4096 + l*16;
    #pragma unroll
    for (int i=0;i<4;i++){
      GLD_LDS(gA + i*1024, dA + i*1024);
      GLD_LDS(gT + i*1024, dT + i*1024);
    }
  };

  dma(0, 0);

  // B-frag (v): lane holds q = q0+row; step s covers d = 16s + 8*hi + j
  half8 v8[16];
  const int q0 = qb*128 + w*32;
  {
    const float* vp = v + (size_t)(q0 + row)*N1 + 8*hi;
    #pragma unroll
    for (int s=0;s<16;s++){
      const float4 a = *(const float4*)(vp + 16*s);
      const float4 b = *(const float4*)(vp + 16*s + 4);
      half8 hv;
      hv[0]=(_Float16)a.x; hv[1]=(_Float16)a.y; hv[2]=(_Float16)a.z; hv[3]=(_Float16)a.w;
      hv[4]=(_Float16)b.x; hv[5]=(_Float16)b.y; hv[6]=(_Float16)b.z; hv[7]=(_Float16)b.w;
      v8[s]=hv;
    }
  }

  float mrun = -INFINITY, lrun = 0.f;
  f32x16 oacc[8];
  #pragma unroll
  for (int b=0;b<8;b++) oacc[b] = (f32x16)(0.f);

  // QK^T A base: row*512, granule (2s+hi)^(row&7); xor-folded base
  const int e7 = row & 7;
  const uint32 qkB = (uint32)(row*512 + ((hi ^ (e7 & 1)) << 4) + ((e7 >> 1) << 5));
  // PV A base: row*64, granule (2k+hi)^((row>>1)&3)
  const int sd = (row >> 1) & 3;
  const uint32 pvB = (uint32)(row*64 + ((hi ^ (sd & 1)) << 4) + ((sd >> 1) << 5));

  __syncthreads();

  for (int tt=0; tt<nt; ++tt){
    const int buf = tt & 1;
    const bool pf = (tt+1 < nt);
    if (pf) dma(tt+1, buf^1);

    // m2 for this lane's 16 pattern-rows: rows (r&3)+8(r>>2)+4hi
    const float* m2p = m2g + c*CK + tt*KT;
    f32x4 m2v[4];
    #pragma unroll
    for (int b=0;b<4;b++) m2v[b] = *(const f32x4*)(m2p + 8*b + 4*hi);

    // ---- QK^T: S^T[pat][q], A = rowA (pattern rows), B = v8 ----
    const char* ra = lds + RA_OFF + buf*TILE_B;
    f32x16 S = (f32x16)(0.f);
    #pragma unroll
    for (int s=0;s<16;s++){
      const half8 a = *(const half8*)(ra + (qkB ^ (uint32)(s<<5)));
      S = __builtin_amdgcn_mfma_f32_32x32x16_f16(a, v8[s], S, 0,0,0);
    }

    float p[16];
    #pragma unroll
    for (int r=0;r<16;r++) p[r] = S[r] + m2v[r>>2][r&3];

    // ---- online softmax: lane owns column q; rows split with lane l^32 ----
    float tm = p[0];
    #pragma unroll
    for (int r=1;r<16;r++) tm = fmaxf(tm, p[r]);
    tm = fmaxf(tm, __shfl_xor(tm, 32));
    if (__any(tm > mrun + 8.0f)){
      const float nm = fmaxf(mrun, tm);
      const float sc = __expf(mrun - nm);
      lrun *= sc; mrun = nm;
      #pragma unroll
      for (int b=0;b<8;b++) oacc[b] *= sc;    // per-lane scalar: q is the lane col
    }
    #pragma unroll
    for (int r=0;r<16;r++) p[r] = __expf(p[r] - mrun);
    float ps = 0.f;
    #pragma unroll
    for (int r=0;r<16;r++) ps += p[r];
    ps += __shfl_xor(ps, 32); lrun += ps;

    // ---- P -> f16 B-frags in-register (no LDS): pack pairs, exchange halves ----
    uint32 D[8];
    #pragma unroll
    for (int i=0;i<8;i++){
      union { __fp16 h2 __attribute__((ext_vector_type(2))); uint32 u; } cv;
      cv.h2 = __builtin_amdgcn_cvt_pkrtz(p[2*i], p[2*i+1]);
      D[i] = cv.u;
    }
    // lane's S rows: lo={0-3,8-11,16-19,24-27}, hi=+4. B-frag k-step1 needs pats
    // (8*hi..+7): w0..w3; k-step2: pats 16+8*hi..+7: w4..w7.
    uint32 wq[8];
    {
      const uint32 tD0 = (uint32)__shfl_xor((int)D[0], 32);
      const uint32 tD1 = (uint32)__shfl_xor((int)D[1], 32);
      const uint32 tD2 = (uint32)__shfl_xor((int)D[2], 32);
      const uint32 tD3 = (uint32)__shfl_xor((int)D[3], 32);
      const uint32 tD4 = (uint32)__shfl_xor((int)D[4], 32);
      const uint32 tD5 = (uint32)__shfl_xor((int)D[5], 32);
      const uint32 tD6 = (uint32)__shfl_xor((int)D[6], 32);
      const uint32 tD7 = (uint32)__shfl_xor((int)D[7], 32);
      const bool lo = (hi == 0);
      wq[0] = lo ? D[0] : tD2;  wq[1] = lo ? D[1] : tD3;
      wq[2] = lo ? tD0 : D[2];  wq[3] = lo ? tD1 : D[3];
      wq[4] = lo ? D[4] : tD6;  wq[5] = lo ? D[5] : tD7;
      wq[6] = lo ? tD4 : D[6];  wq[7] = lo ? tD5 : D[7];
    }
    union { uint32 u[4]; half8 h; } pb1, pb2;
    pb1.u[0]=wq[0]; pb1.u[1]=wq[1]; pb1.u[2]=wq[2]; pb1.u[3]=wq[3];
    pb2.u[0]=wq[4]; pb2.u[1]=wq[5]; pb2.u[2]=wq[6]; pb2.u[3]=wq[7];

    // ---- PV (transposed): O^T[d][q] += MemT[d][pat] * P[pat][q] ----
    const char* mtb = lds + MT_OFF + buf*TILE_B;
    const char* a1 = (const char*)(mtb + pvB);
    const char* a2 = (const char*)(mtb + (pvB ^ 32u));
    #pragma unroll
    for (int b=0;b<8;b++){
      const half8 A1 = *(const half8*)(a1 + b*2048);
      oacc[b] = __builtin_amdgcn_mfma_f32_32x32x16_f16(A1, pb1.h, oacc[b], 0,0,0);
      const half8 A2 = *(const half8*)(a2 + b*2048);
      oacc[b] = __builtin_amdgcn_mfma_f32_32x32x16_f16(A2, pb2.h, oacc[b], 0,0,0);
    }

    __syncthreads();
  }

  // ---- partials: Opart[c][d][q] (coalesced along q = lane), m/l from lanes<32 ----
  {
    __hip_bfloat16* Op = Opart + (size_t)c*N1*BQ + (q0 + row);
    #pragma unroll
    for (int b=0;b<8;b++){
      #pragma unroll
      for (int r=0;r<16;r++){
        const int d = 32*b + (r&3) + 8*(r>>2) + 4*hi;
        Op[(size_t)d*BQ] = __float2bfloat16(oacc[b][r]);
      }
    }
    if (hi == 0){
      mpart[(size_t)c*BQ + q0 + row] = mrun;
      lpart[(size_t)c*BQ + q0 + row] = lrun;
    }
  }
}

// ---- reduce: grid = d (256 blocks), threads = q (512) ----
__global__ __launch_bounds__(512) void mhn_reduce_k(
    const float* __restrict__ v, const float* __restrict__ mask,
    const __hip_bfloat16* __restrict__ Opart, const float* __restrict__ mpart,
    const float* __restrict__ lpart, float* __restrict__ out, int nchunk)
{
  const int d = blockIdx.x;
  const int q = threadIdx.x;
  float M = -INFINITY;
  for (int c2=0;c2<nchunk;c2++) M = fmaxf(M, mpart[(size_t)c2*BQ + q]);
  float L = 0.f, o = 0.f;
  for (int c2=0;c2<nchunk;c2++){
    const float e = __expf(mpart[(size_t)c2*BQ + q] - M);
    L += lpart[(size_t)c2*BQ + q]*e;
    o += __bfloat162float(Opart[((size_t)c2*N1 + d)*BQ + q])*e;
  }
  const float vv = v[(size_t)q*N1 + d], mk = mask[(size_t)q*N1 + d];
  out[(size_t)q*N1 + d] = vv + 0.5f*((o/L) - vv)*mk;
}

extern "C" void kernel_launch(void* const* d_in, const int* in_sizes, int n_in,
                              void* d_out, int out_size, void* d_ws, size_t ws_size,
                              hipStream_t stream)
{
  (void)in_sizes; (void)n_in; (void)out_size;
  const float* v    = (const float*)d_in[0];
  const float* mask = (const float*)d_in[1];
  const float* Mem  = (const float*)d_in[2];
  float* out = (float*)d_out;

  const size_t fixedB   = (size_t)N2T*N1*2*2 + (size_t)N2T*4;
  const size_t perChunk = (size_t)BQ*N1*2 + (size_t)BQ*8;
  int nchunk = 128;
  while (nchunk > 4 && fixedB + (size_t)nchunk*perChunk > ws_size) nchunk >>= 1;

  char* wsb = (char*)d_ws;
  _Float16* MemA = (_Float16*)wsb;
  _Float16* MemT = (_Float16*)(wsb + (size_t)N2T*N1*2);
  float*    m2g  = (float*)(wsb + (size_t)N2T*N1*4);
  char* pb = wsb + fixedB;
  __hip_bfloat16* Opart = (__hip_bfloat16*)pb;
  float* mpart = (float*)(pb + (size_t)nchunk*BQ*N1*2);
  float* lpart = mpart + (size_t)nchunk*BQ;

  const int CK = N2T / nchunk;
  const int nt = CK / KT;

  mhn_prep_k<<<dim3(N2T/KT), dim3(256), 0, stream>>>(Mem, MemA, MemT, m2g);
  mhn_flash_k<<<dim3(4*nchunk), dim3(256), 0, stream>>>(MemA, MemT, m2g, v, Opart, mpart, lpart, CK, nt);
  mhn_reduce_k<<<dim3(N1), dim3(BQ), 0, stream>>>(v, mask, Opart, mpart, lpart, out, nchunk);
}

// Round 6
// 69.420 us; speedup vs baseline: 1.5891x; 1.5891x over previous
//
#include <hip/hip_runtime.h>
#include <hip/hip_bf16.h>
#include <stdint.h>

typedef float  f32x4  __attribute__((ext_vector_type(4)));
typedef float  f32x16 __attribute__((ext_vector_type(16)));
typedef _Float16 half8 __attribute__((ext_vector_type(8)));
typedef unsigned int uint32;

#define N1 256
#define N2T 32768
#define BQ 512
#define KT 32
#define TILE_B 16384

// flash LDS: rowA [2][16384] @0 (32 pat rows x 512B, granule g at g^(r&7))
//            memT [2][16384] @32768 (256 d rows x 64B, granule g at g^((d>>1)&3))
#define RA_OFF 0
#define MT_OFF 32768
#define LDS_BYTES 65536

union H4 { _Float16 h[4]; unsigned short s[4]; uint2 u2; };

#define GLD_LDS(gp, lp) __builtin_amdgcn_global_load_lds( \
    (const __attribute__((address_space(1))) void*)(gp), \
    (__attribute__((address_space(3))) void*)(lp), 16, 0, 0)

// ---- prep: Mem f32 -> MemA / MemT (f16, pre-swizzled) + m2 (exact f32). ----
__global__ __launch_bounds__(256) void mhn_prep_k(
    const float* __restrict__ Mem, _Float16* __restrict__ MemA,
    _Float16* __restrict__ MemT, float* __restrict__ m2g)
{
  const int t   = blockIdx.x;
  const int tid = threadIdx.x;
  const int a    = tid >> 4;
  const int dblk = tid & 15;
  const int r0i  = 32*t + 2*a;

  const float* p0 = Mem + (size_t)r0i*N1 + dblk*16;
  const float* p1 = p0 + N1;
  float4 x0[4], x1[4];
  #pragma unroll
  for (int i=0;i<4;i++){ x0[i] = *(const float4*)(p0+4*i); x1[i] = *(const float4*)(p1+4*i); }

  float s0=0.f, s1=0.f;
  H4 h0[4], h1[4];
  #pragma unroll
  for (int i=0;i<4;i++){
    s0 += x0[i].x*x0[i].x + x0[i].y*x0[i].y + x0[i].z*x0[i].z + x0[i].w*x0[i].w;
    s1 += x1[i].x*x1[i].x + x1[i].y*x1[i].y + x1[i].z*x1[i].z + x1[i].w*x1[i].w;
    h0[i].h[0]=(_Float16)x0[i].x; h0[i].h[1]=(_Float16)x0[i].y; h0[i].h[2]=(_Float16)x0[i].z; h0[i].h[3]=(_Float16)x0[i].w;
    h1[i].h[0]=(_Float16)x1[i].x; h1[i].h[1]=(_Float16)x1[i].y; h1[i].h[2]=(_Float16)x1[i].z; h1[i].h[3]=(_Float16)x1[i].w;
  }

  char* bA = (char*)MemA + (size_t)t*TILE_B;
  {
    const int e0 = (2*a)&7, e1 = (2*a+1)&7;
    uint4 wv;
    wv.x=h0[0].u2.x; wv.y=h0[0].u2.y; wv.z=h0[1].u2.x; wv.w=h0[1].u2.y;
    *(uint4*)(bA + (2*a)*512   + (((2*dblk  )^e0)<<4)) = wv;
    wv.x=h0[2].u2.x; wv.y=h0[2].u2.y; wv.z=h0[3].u2.x; wv.w=h0[3].u2.y;
    *(uint4*)(bA + (2*a)*512   + (((2*dblk+1)^e0)<<4)) = wv;
    wv.x=h1[0].u2.x; wv.y=h1[0].u2.y; wv.z=h1[1].u2.x; wv.w=h1[1].u2.y;
    *(uint4*)(bA + (2*a+1)*512 + (((2*dblk  )^e1)<<4)) = wv;
    wv.x=h1[2].u2.x; wv.y=h1[2].u2.y; wv.z=h1[3].u2.x; wv.w=h1[3].u2.y;
    *(uint4*)(bA + (2*a+1)*512 + (((2*dblk+1)^e1)<<4)) = wv;
  }

  char* bT = (char*)MemT + (size_t)t*TILE_B;
  #pragma unroll
  for (int i=0;i<4;i++){
    #pragma unroll
    for (int j=0;j<4;j++){
      const int d = dblk*16 + 4*i + j;
      const uint32 pk = (uint32)h0[i].s[j] | ((uint32)h1[i].s[j] << 16);
      *(uint32*)(bT + d*64 + ((((a>>2) ^ ((d>>1)&3)))<<4) + ((a&3)<<2)) = pk;
    }
  }

  s0 += __shfl_xor(s0,1); s0 += __shfl_xor(s0,2); s0 += __shfl_xor(s0,4); s0 += __shfl_xor(s0,8);
  s1 += __shfl_xor(s1,1); s1 += __shfl_xor(s1,2); s1 += __shfl_xor(s1,4); s1 += __shfl_xor(s1,8);
  if (dblk == 0){ m2g[r0i] = -0.5f*s0; m2g[r0i+1] = -0.5f*s1; }
}

// ---- flash: 32x32x16 MFMA; wave owns 32 q; O computed transposed (rows=d, cols=q) ----
__global__ __launch_bounds__(256, 2) void mhn_flash_k(
    const _Float16* __restrict__ MemA, const _Float16* __restrict__ MemT,
    const float* __restrict__ m2g, const float* __restrict__ v,
    __hip_bfloat16* __restrict__ Opart, float* __restrict__ mpart,
    float* __restrict__ lpart, int CK, int nt)
{
  __shared__ __align__(16) char lds[LDS_BYTES];

  const int tid = threadIdx.x;
  const int w   = tid >> 6;
  const int l   = tid & 63;
  const int row = l & 31;
  const int hi  = l >> 5;

  const int nwg = gridDim.x;
  const int bid = blockIdx.x;
  const int s_  = (bid & 7) * (nwg >> 3) + (bid >> 3);
  const int c   = s_ >> 2;
  const int qb  = s_ & 3;

  auto dma = [&](int tt, int bw){
    const size_t off = (size_t)(c*(CK>>5) + tt)*TILE_B + w*4096 + l*16;
    const char* gA = (const char*)MemA + off;
    const char* gT = (const char*)MemT + off;
    char* dA = lds + RA_OFF + bw*TILE_B + w*4096 + l*16;
    char* dT = lds + MT_OFF + bw*TILE_B + w*4096 + l*16;
    #pragma unroll
    for (int i=0;i<4;i++){
      GLD_LDS(gA + i*1024, dA + i*1024);
      GLD_LDS(gT + i*1024, dT + i*1024);
    }
  };

  dma(0, 0);

  half8 v8[16];
  const int q0 = qb*128 + w*32;
  {
    const float* vp = v + (size_t)(q0 + row)*N1 + 8*hi;
    #pragma unroll
    for (int s=0;s<16;s++){
      const float4 a = *(const float4*)(vp + 16*s);
      const float4 b = *(const float4*)(vp + 16*s + 4);
      half8 hv;
      hv[0]=(_Float16)a.x; hv[1]=(_Float16)a.y; hv[2]=(_Float16)a.z; hv[3]=(_Float16)a.w;
      hv[4]=(_Float16)b.x; hv[5]=(_Float16)b.y; hv[6]=(_Float16)b.z; hv[7]=(_Float16)b.w;
      v8[s]=hv;
    }
  }

  float mrun = -INFINITY, lrun = 0.f;
  f32x16 oacc[8];
  #pragma unroll
  for (int b=0;b<8;b++) oacc[b] = (f32x16)(0.f);

  const int e7 = row & 7;
  const uint32 qkB = (uint32)(row*512 + ((hi ^ (e7 & 1)) << 4) + ((e7 >> 1) << 5));
  const int sd = (row >> 1) & 3;
  const uint32 pvB = (uint32)(row*64 + ((hi ^ (sd & 1)) << 4) + ((sd >> 1) << 5));

  __syncthreads();

  for (int tt=0; tt<nt; ++tt){
    const int buf = tt & 1;
    const bool pf = (tt+1 < nt);
    if (pf) dma(tt+1, buf^1);

    const float* m2p = m2g + c*CK + tt*KT;
    f32x4 m2v[4];
    #pragma unroll
    for (int b=0;b<4;b++) m2v[b] = *(const f32x4*)(m2p + 8*b + 4*hi);

    const char* ra = lds + RA_OFF + buf*TILE_B;
    f32x16 S = (f32x16)(0.f);
    #pragma unroll
    for (int s=0;s<16;s++){
      const half8 a = *(const half8*)(ra + (qkB ^ (uint32)(s<<5)));
      S = __builtin_amdgcn_mfma_f32_32x32x16_f16(a, v8[s], S, 0,0,0);
    }

    float p[16];
    #pragma unroll
    for (int r=0;r<16;r++) p[r] = S[r] + m2v[r>>2][r&3];

    float tm = p[0];
    #pragma unroll
    for (int r=1;r<16;r++) tm = fmaxf(tm, p[r]);
    tm = fmaxf(tm, __shfl_xor(tm, 32));
    if (__any(tm > mrun + 8.0f)){
      const float nm = fmaxf(mrun, tm);
      const float sc = __expf(mrun - nm);
      lrun *= sc; mrun = nm;
      #pragma unroll
      for (int b=0;b<8;b++) oacc[b] *= sc;
    }
    #pragma unroll
    for (int r=0;r<16;r++) p[r] = __expf(p[r] - mrun);
    float ps = 0.f;
    #pragma unroll
    for (int r=0;r<16;r++) ps += p[r];
    ps += __shfl_xor(ps, 32); lrun += ps;

    uint32 D[8];
    #pragma unroll
    for (int i=0;i<8;i++){
      union { __fp16 h2 __attribute__((ext_vector_type(2))); uint32 u; } cv;
      cv.h2 = __builtin_amdgcn_cvt_pkrtz(p[2*i], p[2*i+1]);
      D[i] = cv.u;
    }
    uint32 wq[8];
    {
      const uint32 tD0 = (uint32)__shfl_xor((int)D[0], 32);
      const uint32 tD1 = (uint32)__shfl_xor((int)D[1], 32);
      const uint32 tD2 = (uint32)__shfl_xor((int)D[2], 32);
      const uint32 tD3 = (uint32)__shfl_xor((int)D[3], 32);
      const uint32 tD4 = (uint32)__shfl_xor((int)D[4], 32);
      const uint32 tD5 = (uint32)__shfl_xor((int)D[5], 32);
      const uint32 tD6 = (uint32)__shfl_xor((int)D[6], 32);
      const uint32 tD7 = (uint32)__shfl_xor((int)D[7], 32);
      const bool lo = (hi == 0);
      wq[0] = lo ? D[0] : tD2;  wq[1] = lo ? D[1] : tD3;
      wq[2] = lo ? tD0 : D[2];  wq[3] = lo ? tD1 : D[3];
      wq[4] = lo ? D[4] : tD6;  wq[5] = lo ? D[5] : tD7;
      wq[6] = lo ? tD4 : D[6];  wq[7] = lo ? tD5 : D[7];
    }
    union { uint32 u[4]; half8 h; } pb1, pb2;
    pb1.u[0]=wq[0]; pb1.u[1]=wq[1]; pb1.u[2]=wq[2]; pb1.u[3]=wq[3];
    pb2.u[0]=wq[4]; pb2.u[1]=wq[5]; pb2.u[2]=wq[6]; pb2.u[3]=wq[7];

    const char* mtb = lds + MT_OFF + buf*TILE_B;
    const char* a1 = (const char*)(mtb + pvB);
    const char* a2 = (const char*)(mtb + (pvB ^ 32u));
    #pragma unroll
    for (int b=0;b<8;b++){
      const half8 A1 = *(const half8*)(a1 + b*2048);
      oacc[b] = __builtin_amdgcn_mfma_f32_32x32x16_f16(A1, pb1.h, oacc[b], 0,0,0);
      const half8 A2 = *(const half8*)(a2 + b*2048);
      oacc[b] = __builtin_amdgcn_mfma_f32_32x32x16_f16(A2, pb2.h, oacc[b], 0,0,0);
    }

    __syncthreads();
  }

  {
    __hip_bfloat16* Op = Opart + (size_t)c*N1*BQ + (q0 + row);
    #pragma unroll
    for (int b=0;b<8;b++){
      #pragma unroll
      for (int r=0;r<16;r++){
        const int d = 32*b + (r&3) + 8*(r>>2) + 4*hi;
        Op[(size_t)d*BQ] = __float2bfloat16(oacc[b][r]);
      }
    }
    if (hi == 0){
      mpart[(size_t)c*BQ + q0 + row] = mrun;
      lpart[(size_t)c*BQ + q0 + row] = lrun;
    }
  }
}

// ---- stage A: per-q global softmax stats -> W[c][q] = exp(m_c - M_q), invL[q] ----
__global__ __launch_bounds__(128) void mhn_wprep_k(
    const float* __restrict__ mpart, const float* __restrict__ lpart,
    float* __restrict__ W, float* __restrict__ invL, int nchunk)
{
  __shared__ float sred[2];
  const int q = blockIdx.x;
  const int c = threadIdx.x;
  const int l = c & 63, wv = c >> 6;

  const float m = (c < nchunk) ? mpart[(size_t)c*BQ + q] : -INFINITY;
  const float lv = (c < nchunk) ? lpart[(size_t)c*BQ + q] : 0.f;

  float r = m;
  r = fmaxf(r, __shfl_xor(r,1));  r = fmaxf(r, __shfl_xor(r,2));
  r = fmaxf(r, __shfl_xor(r,4));  r = fmaxf(r, __shfl_xor(r,8));
  r = fmaxf(r, __shfl_xor(r,16)); r = fmaxf(r, __shfl_xor(r,32));
  if (l == 0) sred[wv] = r;
  __syncthreads();
  const float M = fmaxf(sred[0], sred[1]);
  __syncthreads();

  const float e = __expf(m - M);
  float s = lv * e;
  s += __shfl_xor(s,1);  s += __shfl_xor(s,2);
  s += __shfl_xor(s,4);  s += __shfl_xor(s,8);
  s += __shfl_xor(s,16); s += __shfl_xor(s,32);
  if (l == 0) sred[wv] = s;
  __syncthreads();

  if (c < nchunk) W[(size_t)c*BQ + q] = e;
  if (c == 0) invL[q] = 1.0f / (sred[0] + sred[1]);
}

// ---- stage B: out[q][d] = v + 0.5*mask*(invL_q * sum_c W[c][q]*O[c][d][q] - v) ----
__global__ __launch_bounds__(256) void mhn_wsum_k(
    const float* __restrict__ v, const float* __restrict__ mask,
    const __hip_bfloat16* __restrict__ Opart, const float* __restrict__ W,
    const float* __restrict__ invL, float* __restrict__ out, int nchunk)
{
  const int g = blockIdx.x*256 + threadIdx.x;
  const int q = g & (BQ-1);
  const int d = g >> 9;

  const __hip_bfloat16* op = Opart + (size_t)d*BQ + q;
  const float* wp = W + q;
  float acc = 0.f;
  #pragma unroll 8
  for (int c2=0; c2<nchunk; c2++){
    acc += __bfloat162float(op[(size_t)c2*N1*BQ]) * wp[(size_t)c2*BQ];
  }
  const float vv = v[(size_t)q*N1 + d], mk = mask[(size_t)q*N1 + d];
  out[(size_t)q*N1 + d] = vv + 0.5f*(acc*invL[q] - vv)*mk;
}

extern "C" void kernel_launch(void* const* d_in, const int* in_sizes, int n_in,
                              void* d_out, int out_size, void* d_ws, size_t ws_size,
                              hipStream_t stream)
{
  (void)in_sizes; (void)n_in; (void)out_size;
  const float* v    = (const float*)d_in[0];
  const float* mask = (const float*)d_in[1];
  const float* Mem  = (const float*)d_in[2];
  float* out = (float*)d_out;

  // ws: MemA f16 | MemT f16 | m2 f32 | invL f32 | Opart bf16 | mpart | lpart | W
  const size_t fixedB   = (size_t)N2T*N1*2*2 + (size_t)N2T*4 + (size_t)BQ*4;
  const size_t perChunk = (size_t)BQ*N1*2 + (size_t)BQ*12;
  int nchunk = 128;
  while (nchunk > 4 && fixedB + (size_t)nchunk*perChunk > ws_size) nchunk >>= 1;

  char* wsb = (char*)d_ws;
  _Float16* MemA = (_Float16*)wsb;
  _Float16* MemT = (_Float16*)(wsb + (size_t)N2T*N1*2);
  float*    m2g  = (float*)(wsb + (size_t)N2T*N1*4);
  float*    invL = (float*)(wsb + (size_t)N2T*N1*4 + (size_t)N2T*4);
  char* pb = wsb + fixedB;
  __hip_bfloat16* Opart = (__hip_bfloat16*)pb;
  float* mpart = (float*)(pb + (size_t)nchunk*BQ*N1*2);
  float* lpart = mpart + (size_t)nchunk*BQ;
  float* W     = lpart + (size_t)nchunk*BQ;

  const int CK = N2T / nchunk;
  const int nt = CK / KT;

  mhn_prep_k<<<dim3(N2T/KT), dim3(256), 0, stream>>>(Mem, MemA, MemT, m2g);
  mhn_flash_k<<<dim3(4*nchunk), dim3(256), 0, stream>>>(MemA, MemT, m2g, v, Opart, mpart, lpart, CK, nt);
  mhn_wprep_k<<<dim3(BQ), dim3(128), 0, stream>>>(mpart, lpart, W, invL, nchunk);
  mhn_wsum_k<<<dim3((N1*BQ)/256), dim3(256), 0, stream>>>(v, mask, Opart, W, invL, out, nchunk);
}

// Round 7
// 69.403 us; speedup vs baseline: 1.5895x; 1.0002x over previous
//
#include <hip/hip_runtime.h>
#include <hip/hip_bf16.h>
#include <stdint.h>

typedef float  f32x4  __attribute__((ext_vector_type(4)));
typedef float  f32x16 __attribute__((ext_vector_type(16)));
typedef _Float16 half8 __attribute__((ext_vector_type(8)));
typedef unsigned int uint32;

#define N1 256
#define N2T 32768
#define BQ 512
#define KT 32
#define TILE_B 16384

// flash LDS: rowA [2][16384] @0 (32 pat rows x 512B, granule g at g^(r&7))
//            memT [2][16384] @32768 (256 d rows x 64B, granule g at g^((d>>1)&3))
#define RA_OFF 0
#define MT_OFF 32768
#define LDS_BYTES 65536

union H4 { _Float16 h[4]; unsigned short s[4]; uint2 u2; };

#define GLD_LDS(gp, lp) __builtin_amdgcn_global_load_lds( \
    (const __attribute__((address_space(1))) void*)(gp), \
    (__attribute__((address_space(3))) void*)(lp), 16, 0, 0)

// ---- prep: Mem f32 -> MemA / MemT (f16, pre-swizzled) + m2 (exact f32). ----
__global__ __launch_bounds__(256) void mhn_prep_k(
    const float* __restrict__ Mem, _Float16* __restrict__ MemA,
    _Float16* __restrict__ MemT, float* __restrict__ m2g)
{
  const int t   = blockIdx.x;
  const int tid = threadIdx.x;
  const int a    = tid >> 4;
  const int dblk = tid & 15;
  const int r0i  = 32*t + 2*a;

  const float* p0 = Mem + (size_t)r0i*N1 + dblk*16;
  const float* p1 = p0 + N1;
  float4 x0[4], x1[4];
  #pragma unroll
  for (int i=0;i<4;i++){ x0[i] = *(const float4*)(p0+4*i); x1[i] = *(const float4*)(p1+4*i); }

  float s0=0.f, s1=0.f;
  H4 h0[4], h1[4];
  #pragma unroll
  for (int i=0;i<4;i++){
    s0 += x0[i].x*x0[i].x + x0[i].y*x0[i].y + x0[i].z*x0[i].z + x0[i].w*x0[i].w;
    s1 += x1[i].x*x1[i].x + x1[i].y*x1[i].y + x1[i].z*x1[i].z + x1[i].w*x1[i].w;
    h0[i].h[0]=(_Float16)x0[i].x; h0[i].h[1]=(_Float16)x0[i].y; h0[i].h[2]=(_Float16)x0[i].z; h0[i].h[3]=(_Float16)x0[i].w;
    h1[i].h[0]=(_Float16)x1[i].x; h1[i].h[1]=(_Float16)x1[i].y; h1[i].h[2]=(_Float16)x1[i].z; h1[i].h[3]=(_Float16)x1[i].w;
  }

  char* bA = (char*)MemA + (size_t)t*TILE_B;
  {
    const int e0 = (2*a)&7, e1 = (2*a+1)&7;
    uint4 wv;
    wv.x=h0[0].u2.x; wv.y=h0[0].u2.y; wv.z=h0[1].u2.x; wv.w=h0[1].u2.y;
    *(uint4*)(bA + (2*a)*512   + (((2*dblk  )^e0)<<4)) = wv;
    wv.x=h0[2].u2.x; wv.y=h0[2].u2.y; wv.z=h0[3].u2.x; wv.w=h0[3].u2.y;
    *(uint4*)(bA + (2*a)*512   + (((2*dblk+1)^e0)<<4)) = wv;
    wv.x=h1[0].u2.x; wv.y=h1[0].u2.y; wv.z=h1[1].u2.x; wv.w=h1[1].u2.y;
    *(uint4*)(bA + (2*a+1)*512 + (((2*dblk  )^e1)<<4)) = wv;
    wv.x=h1[2].u2.x; wv.y=h1[2].u2.y; wv.z=h1[3].u2.x; wv.w=h1[3].u2.y;
    *(uint4*)(bA + (2*a+1)*512 + (((2*dblk+1)^e1)<<4)) = wv;
  }

  char* bT = (char*)MemT + (size_t)t*TILE_B;
  #pragma unroll
  for (int i=0;i<4;i++){
    #pragma unroll
    for (int j=0;j<4;j++){
      const int d = dblk*16 + 4*i + j;
      const uint32 pk = (uint32)h0[i].s[j] | ((uint32)h1[i].s[j] << 16);
      *(uint32*)(bT + d*64 + ((((a>>2) ^ ((d>>1)&3)))<<4) + ((a&3)<<2)) = pk;
    }
  }

  s0 += __shfl_xor(s0,1); s0 += __shfl_xor(s0,2); s0 += __shfl_xor(s0,4); s0 += __shfl_xor(s0,8);
  s1 += __shfl_xor(s1,1); s1 += __shfl_xor(s1,2); s1 += __shfl_xor(s1,4); s1 += __shfl_xor(s1,8);
  if (dblk == 0){ m2g[r0i] = -0.5f*s0; m2g[r0i+1] = -0.5f*s1; }
}

// ---- flash: 32x32x16 MFMA; wave owns 32 q; O computed transposed (rows=d, cols=q) ----
__global__ __launch_bounds__(256, 2) void mhn_flash_k(
    const _Float16* __restrict__ MemA, const _Float16* __restrict__ MemT,
    const float* __restrict__ m2g, const float* __restrict__ v,
    __hip_bfloat16* __restrict__ Opart, float* __restrict__ mpart,
    float* __restrict__ lpart, int CK, int nt)
{
  __shared__ __align__(16) char lds[LDS_BYTES];

  const int tid = threadIdx.x;
  const int w   = tid >> 6;
  const int l   = tid & 63;
  const int row = l & 31;
  const int hi  = l >> 5;

  const int nwg = gridDim.x;
  const int bid = blockIdx.x;
  const int s_  = (bid & 7) * (nwg >> 3) + (bid >> 3);
  const int c   = s_ >> 2;
  const int qb  = s_ & 3;

  // hoisted staging pointers (advance by constants each iter)
  const uint32 dmaL = (uint32)(w*4096 + l*16);
  const char* gA = (const char*)MemA + (size_t)(c*(CK>>5))*TILE_B + dmaL;
  const char* gT = (const char*)MemT + (size_t)(c*(CK>>5))*TILE_B + dmaL;
  char* const dA0 = lds + RA_OFF + dmaL;
  char* const dT0 = lds + MT_OFF + dmaL;

  // prologue DMA: tile 0 -> buf 0
  #pragma unroll
  for (int i=0;i<4;i++){
    GLD_LDS(gA + i*1024, dA0 + i*1024);
    GLD_LDS(gT + i*1024, dT0 + i*1024);
  }
  gA += TILE_B; gT += TILE_B;

  half8 v8[16];
  const int q0 = qb*128 + w*32;
  {
    const float* vp = v + (size_t)(q0 + row)*N1 + 8*hi;
    #pragma unroll
    for (int s=0;s<16;s++){
      const float4 a = *(const float4*)(vp + 16*s);
      const float4 b = *(const float4*)(vp + 16*s + 4);
      half8 hv;
      hv[0]=(_Float16)a.x; hv[1]=(_Float16)a.y; hv[2]=(_Float16)a.z; hv[3]=(_Float16)a.w;
      hv[4]=(_Float16)b.x; hv[5]=(_Float16)b.y; hv[6]=(_Float16)b.z; hv[7]=(_Float16)b.w;
      v8[s]=hv;
    }
  }

  float mrun = -INFINITY, lrun = 0.f;
  f32x16 oacc[8];
  #pragma unroll
  for (int b=0;b<8;b++) oacc[b] = (f32x16)(0.f);

  const int e7 = row & 7;
  const uint32 qkB = (uint32)(row*512 + ((hi ^ (e7 & 1)) << 4) + ((e7 >> 1) << 5));
  const int sd = (row >> 1) & 3;
  const uint32 pvB = (uint32)(row*64 + ((hi ^ (sd & 1)) << 4) + ((sd >> 1) << 5));

  const float* m2p = m2g + c*CK + 8*0 + 4*hi;   // lane's first m2 group; advance by KT

  __syncthreads();

  for (int tt=0; tt<nt; ++tt){
    const uint32 bufO = (uint32)(tt & 1)*TILE_B;
    const bool pf = (tt+1 < nt);
    if (pf){
      const char* sA = gA; const char* sT = gT;
      char* dA = dA0 + (bufO ^ TILE_B);
      char* dT = dT0 + (bufO ^ TILE_B);
      #pragma unroll
      for (int i=0;i<4;i++){
        GLD_LDS(sA + i*1024, dA + i*1024);
        GLD_LDS(sT + i*1024, dT + i*1024);
      }
      gA += TILE_B; gT += TILE_B;
    }

    f32x4 m2v[4];
    #pragma unroll
    for (int b=0;b<4;b++) m2v[b] = *(const f32x4*)(m2p + 8*b);

    // ---- QK^T: S^T[pat][q] ----
    const char* ra = lds + RA_OFF + bufO;
    f32x16 S = (f32x16)(0.f);
    __builtin_amdgcn_s_setprio(1);
    #pragma unroll
    for (int s=0;s<16;s++){
      const half8 a = *(const half8*)(ra + (qkB ^ (uint32)(s<<5)));
      S = __builtin_amdgcn_mfma_f32_32x32x16_f16(a, v8[s], S, 0,0,0);
    }
    __builtin_amdgcn_s_setprio(0);

    float p[16];
    #pragma unroll
    for (int r=0;r<16;r++) p[r] = S[r] + m2v[r>>2][r&3];

    // ---- online softmax (pairwise trees) ----
    float t01=fmaxf(p[0],p[1]),   t23=fmaxf(p[2],p[3]),   t45=fmaxf(p[4],p[5]),   t67=fmaxf(p[6],p[7]);
    float t89=fmaxf(p[8],p[9]),   tAB=fmaxf(p[10],p[11]), tCD=fmaxf(p[12],p[13]), tEF=fmaxf(p[14],p[15]);
    float q03=fmaxf(t01,t23), q47=fmaxf(t45,t67), q8B=fmaxf(t89,tAB), qCF=fmaxf(tCD,tEF);
    float tm = fmaxf(fmaxf(q03,q47), fmaxf(q8B,qCF));
    tm = fmaxf(tm, __shfl_xor(tm, 32));
    if (__any(tm > mrun + 8.0f)){
      const float nm = fmaxf(mrun, tm);
      const float sc = __expf(mrun - nm);
      lrun *= sc; mrun = nm;
      #pragma unroll
      for (int b=0;b<8;b++) oacc[b] *= sc;
    }
    #pragma unroll
    for (int r=0;r<16;r++) p[r] = __expf(p[r] - mrun);

    // ---- P -> f16 B-frags in-register (pack first so PV can issue early) ----
    uint32 D[8];
    #pragma unroll
    for (int i=0;i<8;i++){
      union { __fp16 h2 __attribute__((ext_vector_type(2))); uint32 u; } cv;
      cv.h2 = __builtin_amdgcn_cvt_pkrtz(p[2*i], p[2*i+1]);
      D[i] = cv.u;
    }
    uint32 wq[8];
    {
      const uint32 tD0 = (uint32)__shfl_xor((int)D[0], 32);
      const uint32 tD1 = (uint32)__shfl_xor((int)D[1], 32);
      const uint32 tD2 = (uint32)__shfl_xor((int)D[2], 32);
      const uint32 tD3 = (uint32)__shfl_xor((int)D[3], 32);
      const uint32 tD4 = (uint32)__shfl_xor((int)D[4], 32);
      const uint32 tD5 = (uint32)__shfl_xor((int)D[5], 32);
      const uint32 tD6 = (uint32)__shfl_xor((int)D[6], 32);
      const uint32 tD7 = (uint32)__shfl_xor((int)D[7], 32);
      const bool lo = (hi == 0);
      wq[0] = lo ? D[0] : tD2;  wq[1] = lo ? D[1] : tD3;
      wq[2] = lo ? tD0 : D[2];  wq[3] = lo ? tD1 : D[3];
      wq[4] = lo ? D[4] : tD6;  wq[5] = lo ? D[5] : tD7;
      wq[6] = lo ? tD4 : D[6];  wq[7] = lo ? tD5 : D[7];
    }
    union { uint32 u[4]; half8 h; } pb1, pb2;
    pb1.u[0]=wq[0]; pb1.u[1]=wq[1]; pb1.u[2]=wq[2]; pb1.u[3]=wq[3];
    pb2.u[0]=wq[4]; pb2.u[1]=wq[5]; pb2.u[2]=wq[6]; pb2.u[3]=wq[7];

    // ---- PV (transposed): O^T[d][q] += MemT[d][pat] * P[pat][q] ----
    const char* mtb = lds + MT_OFF + bufO;
    const char* a1 = (const char*)(mtb + pvB);
    const char* a2 = (const char*)(mtb + (pvB ^ 32u));
    __builtin_amdgcn_s_setprio(1);
    #pragma unroll
    for (int b=0;b<8;b++){
      const half8 A1 = *(const half8*)(a1 + b*2048);
      oacc[b] = __builtin_amdgcn_mfma_f32_32x32x16_f16(A1, pb1.h, oacc[b], 0,0,0);
      const half8 A2 = *(const half8*)(a2 + b*2048);
      oacc[b] = __builtin_amdgcn_mfma_f32_32x32x16_f16(A2, pb2.h, oacc[b], 0,0,0);
    }
    __builtin_amdgcn_s_setprio(0);

    // ---- l-sum (pairwise tree), off the PV critical path ----
    float s01=p[0]+p[1],   s23=p[2]+p[3],   s45=p[4]+p[5],   s67=p[6]+p[7];
    float s89=p[8]+p[9],   sAB=p[10]+p[11], sCD=p[12]+p[13], sEF=p[14]+p[15];
    float u03=s01+s23, u47=s45+s67, u8B=s89+sAB, uCF=sCD+sEF;
    float ps = (u03+u47) + (u8B+uCF);
    ps += __shfl_xor(ps, 32); lrun += ps;

    m2p += KT;
    __syncthreads();
  }

  {
    __hip_bfloat16* Op = Opart + (size_t)c*N1*BQ + (q0 + row);
    #pragma unroll
    for (int b=0;b<8;b++){
      #pragma unroll
      for (int r=0;r<16;r++){
        const int d = 32*b + (r&3) + 8*(r>>2) + 4*hi;
        Op[(size_t)d*BQ] = __float2bfloat16(oacc[b][r]);
      }
    }
    if (hi == 0){
      mpart[(size_t)c*BQ + q0 + row] = mrun;
      lpart[(size_t)c*BQ + q0 + row] = lrun;
    }
  }
}

// ---- stage A: per-q global softmax stats -> W[c][q] = exp(m_c - M_q), invL[q] ----
__global__ __launch_bounds__(128) void mhn_wprep_k(
    const float* __restrict__ mpart, const float* __restrict__ lpart,
    float* __restrict__ W, float* __restrict__ invL, int nchunk)
{
  __shared__ float sred[2];
  const int q = blockIdx.x;
  const int c = threadIdx.x;
  const int l = c & 63, wv = c >> 6;

  const float m = (c < nchunk) ? mpart[(size_t)c*BQ + q] : -INFINITY;
  const float lv = (c < nchunk) ? lpart[(size_t)c*BQ + q] : 0.f;

  float r = m;
  r = fmaxf(r, __shfl_xor(r,1));  r = fmaxf(r, __shfl_xor(r,2));
  r = fmaxf(r, __shfl_xor(r,4));  r = fmaxf(r, __shfl_xor(r,8));
  r = fmaxf(r, __shfl_xor(r,16)); r = fmaxf(r, __shfl_xor(r,32));
  if (l == 0) sred[wv] = r;
  __syncthreads();
  const float M = fmaxf(sred[0], sred[1]);
  __syncthreads();

  const float e = __expf(m - M);
  float s = lv * e;
  s += __shfl_xor(s,1);  s += __shfl_xor(s,2);
  s += __shfl_xor(s,4);  s += __shfl_xor(s,8);
  s += __shfl_xor(s,16); s += __shfl_xor(s,32);
  if (l == 0) sred[wv] = s;
  __syncthreads();

  if (c < nchunk) W[(size_t)c*BQ + q] = e;
  if (c == 0) invL[q] = 1.0f / (sred[0] + sred[1]);
}

// ---- stage B: out[q][d] = v + 0.5*mask*(invL_q * sum_c W[c][q]*O[c][d][q] - v) ----
__global__ __launch_bounds__(256) void mhn_wsum_k(
    const float* __restrict__ v, const float* __restrict__ mask,
    const __hip_bfloat16* __restrict__ Opart, const float* __restrict__ W,
    const float* __restrict__ invL, float* __restrict__ out, int nchunk)
{
  const int g = blockIdx.x*256 + threadIdx.x;
  const int q = g & (BQ-1);
  const int d = g >> 9;

  const __hip_bfloat16* op = Opart + (size_t)d*BQ + q;
  const float* wp = W + q;
  float acc = 0.f;
  #pragma unroll 8
  for (int c2=0; c2<nchunk; c2++){
    acc += __bfloat162float(op[(size_t)c2*N1*BQ]) * wp[(size_t)c2*BQ];
  }
  const float vv = v[(size_t)q*N1 + d], mk = mask[(size_t)q*N1 + d];
  out[(size_t)q*N1 + d] = vv + 0.5f*(acc*invL[q] - vv)*mk;
}

extern "C" void kernel_launch(void* const* d_in, const int* in_sizes, int n_in,
                              void* d_out, int out_size, void* d_ws, size_t ws_size,
                              hipStream_t stream)
{
  (void)in_sizes; (void)n_in; (void)out_size;
  const float* v    = (const float*)d_in[0];
  const float* mask = (const float*)d_in[1];
  const float* Mem  = (const float*)d_in[2];
  float* out = (float*)d_out;

  // ws: MemA f16 | MemT f16 | m2 f32 | invL f32 | Opart bf16 | mpart | lpart | W
  const size_t fixedB   = (size_t)N2T*N1*2*2 + (size_t)N2T*4 + (size_t)BQ*4;
  const size_t perChunk = (size_t)BQ*N1*2 + (size_t)BQ*12;
  int nchunk = 128;
  while (nchunk > 4 && fixedB + (size_t)nchunk*perChunk > ws_size) nchunk >>= 1;

  char* wsb = (char*)d_ws;
  _Float16* MemA = (_Float16*)wsb;
  _Float16* MemT = (_Float16*)(wsb + (size_t)N2T*N1*2);
  float*    m2g  = (float*)(wsb + (size_t)N2T*N1*4);
  float*    invL = (float*)(wsb + (size_t)N2T*N1*4 + (size_t)N2T*4);
  char* pb = wsb + fixedB;
  __hip_bfloat16* Opart = (__hip_bfloat16*)pb;
  float* mpart = (float*)(pb + (size_t)nchunk*BQ*N1*2);
  float* lpart = mpart + (size_t)nchunk*BQ;
  float* W     = lpart + (size_t)nchunk*BQ;

  const int CK = N2T / nchunk;
  const int nt = CK / KT;

  mhn_prep_k<<<dim3(N2T/KT), dim3(256), 0, stream>>>(Mem, MemA, MemT, m2g);
  mhn_flash_k<<<dim3(4*nchunk), dim3(256), 0, stream>>>(MemA, MemT, m2g, v, Opart, mpart, lpart, CK, nt);
  mhn_wprep_k<<<dim3(BQ), dim3(128), 0, stream>>>(mpart, lpart, W, invL, nchunk);
  mhn_wsum_k<<<dim3((N1*BQ)/256), dim3(256), 0, stream>>>(v, mask, Opart, W, invL, out, nchunk);
}